// Round 2
// baseline (1033.782 us; speedup 1.0000x reference)
//
#include <hip/hip_runtime.h>
#include <hip/hip_bf16.h>

typedef __attribute__((ext_vector_type(8))) __bf16 bf16x8;
typedef __attribute__((ext_vector_type(4))) float f32x4;
typedef __attribute__((ext_vector_type(4))) unsigned short u16x4;

#define NN 50000
#define NODES 8   // nodes per block -> 64 point rows, 6250 blocks

// ws layout (u16 elements):
//   0      : W0t bf16 [256 n][320 k]   (81920)
//   81920  : W1t bf16 [256 n][256 k]   (65536)
//   147456 : W2t bf16 [256 n][256 k]   (65536)
//   212992 : global split weights (bf16 hi/lo), 106496 elts:
//            +0      Wg0t_h [256 n][256 k]
//            +65536  Wg0t_l
//            +131072 Wg1t_h [128 n][256 k]
//            +163840 Wg1t_l
//            +196608 Wg2t_h [64 n][128 k]
//            +204800 Wg2t_l
#define GW_OFF 212992

__device__ __forceinline__ unsigned short f2bf(float f) {
    unsigned int u = __builtin_bit_cast(unsigned int, f);
    u = (u + 0x7FFFu + ((u >> 16) & 1u)) >> 16;   // RNE; inputs are finite
    return (unsigned short)u;
}
__device__ __forceinline__ float bf2f(unsigned short h) {
    return __builtin_bit_cast(float, (unsigned int)h << 16);
}

// ---------------------------------------------------------------------------
// Prep: point-MLP weights -> bf16 transposed; global-MLP weights -> split
// bf16 hi/lo transposed (fp32-grade MFMA via A_h*W_h + A_l*W_h + A_h*W_l)
// ---------------------------------------------------------------------------
__global__ __launch_bounds__(256) void k_prep(
    const float* __restrict__ W0, const float* __restrict__ W1,
    const float* __restrict__ W2,
    const float* __restrict__ Wg0, const float* __restrict__ Wg1,
    const float* __restrict__ Wg2,
    unsigned short* __restrict__ wbf)
{
    int idx = blockIdx.x * 256 + threadIdx.x;
    if (idx < 81920) {                       // W0t[n][k] = W0[k][n], k<320
        int n = idx / 320, k = idx - n * 320;
        wbf[idx] = f2bf(W0[(size_t)k * 256 + n]);
    } else if (idx < 147456) {               // W1t
        int e = idx - 81920;
        int n = e >> 8, k = e & 255;
        wbf[idx] = f2bf(W1[(size_t)k * 256 + n]);
    } else if (idx < 212992) {               // W2t
        int e = idx - 147456;
        int n = e >> 8, k = e & 255;
        wbf[idx] = f2bf(W2[(size_t)k * 256 + n]);
    } else if (idx < 319488) {               // global weights, split hi/lo
        int e = idx - 212992;                // 0 .. 106495
        float v; int oh, ol;
        if (e < 65536) {                     // Wg0t [256][256]
            int n = e >> 8, k = e & 255;
            v = Wg0[(size_t)k * 256 + n];
            oh = GW_OFF + e; ol = GW_OFF + 65536 + e;
        } else if (e < 98304) {              // Wg1t [128][256]
            int e2 = e - 65536;
            int n = e2 >> 8, k = e2 & 255;
            v = Wg1[(size_t)k * 128 + n];
            oh = GW_OFF + 131072 + e2; ol = GW_OFF + 163840 + e2;
        } else {                             // Wg2t [64][128]
            int e3 = e - 98304;
            int n = e3 >> 7, k = e3 & 127;
            v = Wg2[(size_t)k * 64 + n];
            oh = GW_OFF + 196608 + e3; ol = GW_OFF + 204800 + e3;
        }
        unsigned short h = f2bf(v);
        wbf[oh] = h;
        wbf[ol] = f2bf(v - bf2f(h));
    }
}

// ---------------------------------------------------------------------------
// Fused kernel: global MLP (split-bf16 MFMA) + decoder head + per-point MLP
// per block: 8 nodes = 64 point rows, 4 waves, 3 blocks/CU (LDS 52.5 KB)
//
// LDS union (byte offsets into smem, all lifetimes barrier-separated):
//   0     : xh  [8][264] u16  (stage -> point-L0)
//   4224  : B-union: xl [8][264] (stage->gL0) | q1h/q1l [8][136]x2 (gL1->gL2)
//                    | w3 f32[3][256] (P4->expand)
//   8576  : C-union: gh/gl [8][264]x2 (gL0->gL1) | sP f32[8][256] (L0p->expand)
//   17024 : g2 f32 [8][64]   (gL2 -> decoder)
//   19072 : fb u16 [8][72]   (gL2 -> point-L0, bf16 feats)
//   20224 : rl f32 [8][24]   (decoder -> expand)
//   20992 : hS u16 [64][256] XOR-swizzled (h0 then h1)
//   total 53760 B -> 3 blocks/CU
// ---------------------------------------------------------------------------
__global__ __launch_bounds__(256, 3) void k_fused(
    const float* __restrict__ x,
    const float* __restrict__ bg0, const float* __restrict__ bg1,
    const float* __restrict__ bg2,
    const float* __restrict__ Wdec, const float* __restrict__ bdec,
    const unsigned short* __restrict__ wbf,
    const float* __restrict__ W0f,       // fp32 W0, rows 320..322 (rel cols)
    const float* __restrict__ b0, const float* __restrict__ b1,
    const float* __restrict__ b2,
    float* __restrict__ out_rel, float* __restrict__ out_clu,
    float* __restrict__ out_dec)
{
    __shared__ __attribute__((aligned(16))) unsigned char smem[53760];
    unsigned short* xh  = (unsigned short*)(smem);            // [8][264]
    unsigned short* xl  = (unsigned short*)(smem + 4224);     // [8][264]
    unsigned short* q1h = (unsigned short*)(smem + 4224);     // [8][136]
    unsigned short* q1l = (unsigned short*)(smem + 6400);     // [8][136]
    float*          w3  = (float*)(smem + 4224);              // [3][256]
    unsigned short* gh  = (unsigned short*)(smem + 8576);     // [8][264]
    unsigned short* gl  = (unsigned short*)(smem + 12800);    // [8][264]
    float*          sP  = (float*)(smem + 8576);              // [8][256]
    float*          g2  = (float*)(smem + 17024);             // [8][64]
    unsigned short* fb  = (unsigned short*)(smem + 19072);    // [8][72]
    float*          rl  = (float*)(smem + 20224);             // [8][24]
    unsigned char*  hB  = smem + 20992;                       // [64][256] swz

    const int tid  = threadIdx.x;
    const int lane = tid & 63;
    const int w    = tid >> 6;      // wave id 0..3
    const int quad = lane >> 4;     // 0..3
    const int l15  = lane & 15;
    const int blk  = blockIdx.x;
    const size_t nb = (size_t)blk * NODES;

    // ---- P0: stage x rows, split fp32 -> bf16 hi + lo
    {
        const float4* xg = (const float4*)(x + nb * 256);
        #pragma unroll
        for (int it = 0; it < 2; ++it) {
            int e = tid + it * 256;          // 512 float4 total
            int r = e >> 6, c4 = e & 63;
            float4 v = xg[e];
            u16x4 hv, lv;
            hv[0] = f2bf(v.x); lv[0] = f2bf(v.x - bf2f(hv[0]));
            hv[1] = f2bf(v.y); lv[1] = f2bf(v.y - bf2f(hv[1]));
            hv[2] = f2bf(v.z); lv[2] = f2bf(v.z - bf2f(hv[2]));
            hv[3] = f2bf(v.w); lv[3] = f2bf(v.w - bf2f(hv[3]));
            *(u16x4*)&xh[r * 264 + c4 * 4] = hv;
            *(u16x4*)&xl[r * 264 + c4 * 4] = lv;
        }
    }
    __syncthreads();   // B1

    // ---- P1: global L0 256 -> 256 (rows dup 8->16, drop top)
    {
        const unsigned short* Wh = wbf + GW_OFF;
        const unsigned short* Wl = Wh + 65536;
        f32x4 acc[4];
        f32x4 z = {0.f, 0.f, 0.f, 0.f};
        #pragma unroll
        for (int t = 0; t < 4; ++t) acc[t] = z;
        const int ar = (l15 & 7) * 264;
        for (int ks = 0; ks < 8; ++ks) {
            int k0 = ks * 32 + quad * 8;
            bf16x8 ah = *(const bf16x8*)&xh[ar + k0];
            bf16x8 al = *(const bf16x8*)&xl[ar + k0];
            #pragma unroll
            for (int t = 0; t < 4; ++t) {
                int n = w * 64 + t * 16 + l15;
                bf16x8 bh = *(const bf16x8*)(Wh + (size_t)n * 256 + k0);
                bf16x8 bl = *(const bf16x8*)(Wl + (size_t)n * 256 + k0);
                acc[t] = __builtin_amdgcn_mfma_f32_16x16x32_bf16(ah, bh, acc[t], 0, 0, 0);
                acc[t] = __builtin_amdgcn_mfma_f32_16x16x32_bf16(al, bh, acc[t], 0, 0, 0);
                acc[t] = __builtin_amdgcn_mfma_f32_16x16x32_bf16(ah, bl, acc[t], 0, 0, 0);
            }
        }
        #pragma unroll
        for (int t = 0; t < 4; ++t) {
            int col = w * 64 + t * 16 + l15;
            float bb = bg0[col];
            #pragma unroll
            for (int r = 0; r < 4; ++r) {
                int row = quad * 4 + r;
                if (row < 8) {
                    float v = fmaxf(acc[t][r] + bb, 0.f);
                    unsigned short hv = f2bf(v);
                    gh[row * 264 + col] = hv;
                    gl[row * 264 + col] = f2bf(v - bf2f(hv));
                }
            }
        }
    }
    __syncthreads();   // B2  (xl reads done; q1 writes may now alias it)

    // ---- P2: global L1 256 -> 128
    {
        const unsigned short* Wh = wbf + GW_OFF + 131072;
        const unsigned short* Wl = wbf + GW_OFF + 163840;
        f32x4 acc[2];
        f32x4 z = {0.f, 0.f, 0.f, 0.f};
        acc[0] = z; acc[1] = z;
        const int ar = (l15 & 7) * 264;
        for (int ks = 0; ks < 8; ++ks) {
            int k0 = ks * 32 + quad * 8;
            bf16x8 ah = *(const bf16x8*)&gh[ar + k0];
            bf16x8 al = *(const bf16x8*)&gl[ar + k0];
            #pragma unroll
            for (int t = 0; t < 2; ++t) {
                int n = w * 32 + t * 16 + l15;
                bf16x8 bh = *(const bf16x8*)(Wh + (size_t)n * 256 + k0);
                bf16x8 bl = *(const bf16x8*)(Wl + (size_t)n * 256 + k0);
                acc[t] = __builtin_amdgcn_mfma_f32_16x16x32_bf16(ah, bh, acc[t], 0, 0, 0);
                acc[t] = __builtin_amdgcn_mfma_f32_16x16x32_bf16(al, bh, acc[t], 0, 0, 0);
                acc[t] = __builtin_amdgcn_mfma_f32_16x16x32_bf16(ah, bl, acc[t], 0, 0, 0);
            }
        }
        #pragma unroll
        for (int t = 0; t < 2; ++t) {
            int col = w * 32 + t * 16 + l15;
            float bb = bg1[col];
            #pragma unroll
            for (int r = 0; r < 4; ++r) {
                int row = quad * 4 + r;
                if (row < 8) {
                    float v = fmaxf(acc[t][r] + bb, 0.f);
                    unsigned short hv = f2bf(v);
                    q1h[row * 136 + col] = hv;
                    q1l[row * 136 + col] = f2bf(v - bf2f(hv));
                }
            }
        }
    }
    __syncthreads();   // B3

    // ---- P3: global L2 128 -> 64 ; emit g2 (fp32) + fb (bf16 feats)
    {
        const unsigned short* Wh = wbf + GW_OFF + 196608;
        const unsigned short* Wl = wbf + GW_OFF + 204800;
        f32x4 acc = {0.f, 0.f, 0.f, 0.f};
        const int ar = (l15 & 7) * 136;
        for (int ks = 0; ks < 4; ++ks) {
            int k0 = ks * 32 + quad * 8;
            bf16x8 ah = *(const bf16x8*)&q1h[ar + k0];
            bf16x8 al = *(const bf16x8*)&q1l[ar + k0];
            int n = w * 16 + l15;
            bf16x8 bh = *(const bf16x8*)(Wh + (size_t)n * 128 + k0);
            bf16x8 bl = *(const bf16x8*)(Wl + (size_t)n * 128 + k0);
            acc = __builtin_amdgcn_mfma_f32_16x16x32_bf16(ah, bh, acc, 0, 0, 0);
            acc = __builtin_amdgcn_mfma_f32_16x16x32_bf16(al, bh, acc, 0, 0, 0);
            acc = __builtin_amdgcn_mfma_f32_16x16x32_bf16(ah, bl, acc, 0, 0, 0);
        }
        int col = w * 16 + l15;
        float bb = bg2[col];
        #pragma unroll
        for (int r = 0; r < 4; ++r) {
            int row = quad * 4 + r;
            if (row < 8) {
                float v = fmaxf(acc[r] + bb, 0.f);
                g2[row * 64 + col] = v;
                fb[row * 72 + col] = f2bf(v);
            }
        }
    }
    __syncthreads();   // B4  (q1 reads done; w3 writes may now alias it)

    // ---- P4: decoder head (fp32) -> out_rel + rl ; stage w3 ; cluster ids
    {
        for (int e = tid; e < 768; e += 256)
            w3[e] = W0f[(size_t)(320 + (e >> 8)) * 256 + (e & 255)];
        if (tid < 192) {
            int m = tid / 24, c = tid - m * 24;
            float acc = bdec[c];
            for (int i = 0; i < 64; ++i) acc += g2[m * 64 + i] * Wdec[i * 24 + c];
            out_rel[(size_t)blk * 192 + tid] = acc;
            rl[tid] = acc;
        }
        if (tid < 64)
            out_clu[(size_t)blk * 64 + tid] = (float)(blk * 8 + (tid >> 3));
    }
    __syncthreads();   // B5

    // ---- P5: point L0 MFMA [8(dup16) x 320] -> sP (pre-relu, pre-rel)
    {
        const unsigned short* W0t = wbf;                    // [256 n][320 k]
        f32x4 acc[4];
        f32x4 z = {0.f, 0.f, 0.f, 0.f};
        #pragma unroll
        for (int t = 0; t < 4; ++t) acc[t] = z;
        const int ar8 = lane & 7;
        for (int ks = 0; ks < 8; ++ks) {        // k 0..255 from xh
            int k0 = ks * 32 + quad * 8;
            bf16x8 a = *(const bf16x8*)&xh[ar8 * 264 + k0];
            #pragma unroll
            for (int t = 0; t < 4; ++t) {
                int n = w * 64 + t * 16 + l15;
                bf16x8 b = *(const bf16x8*)(W0t + (size_t)n * 320 + k0);
                acc[t] = __builtin_amdgcn_mfma_f32_16x16x32_bf16(a, b, acc[t], 0, 0, 0);
            }
        }
        #pragma unroll
        for (int ks = 8; ks < 10; ++ks) {       // k 256..319 from fb
            int k0 = ks * 32 + quad * 8;
            bf16x8 a = *(const bf16x8*)&fb[ar8 * 72 + (k0 - 256)];
            #pragma unroll
            for (int t = 0; t < 4; ++t) {
                int n = w * 64 + t * 16 + l15;
                bf16x8 b = *(const bf16x8*)(W0t + (size_t)n * 320 + k0);
                acc[t] = __builtin_amdgcn_mfma_f32_16x16x32_bf16(a, b, acc[t], 0, 0, 0);
            }
        }
        #pragma unroll
        for (int t = 0; t < 4; ++t) {
            int col = w * 64 + t * 16 + l15;
            float bb = b0[col];
            #pragma unroll
            for (int r = 0; r < 4; ++r) {
                int row = quad * 4 + r;
                if (row < 8) sP[row * 256 + col] = acc[t][r] + bb;
            }
        }
    }
    __syncthreads();   // B6

    // ---- P6: expand sP -> h0[64][256] bf16 (XOR-swz) + rank-3 rel + relu
    for (int it = 0; it < 16; ++it) {
        int task = tid + it * 256;          // 64 rows x 64 col-groups
        int row = task >> 6;
        int cg  = task & 63;
        int node = row >> 3, p = row & 7;
        float4 sv = *(const float4*)&sP[node * 256 + cg * 4];
        float ra = rl[node * 24 + p * 3 + 0];
        float rb = rl[node * 24 + p * 3 + 1];
        float rc = rl[node * 24 + p * 3 + 2];
        float4 wa  = *(const float4*)&w3[cg * 4];
        float4 wbv = *(const float4*)&w3[256 + cg * 4];
        float4 wc  = *(const float4*)&w3[512 + cg * 4];
        float v0 = fmaxf(sv.x + ra * wa.x + rb * wbv.x + rc * wc.x, 0.f);
        float v1 = fmaxf(sv.y + ra * wa.y + rb * wbv.y + rc * wc.y, 0.f);
        float v2 = fmaxf(sv.z + ra * wa.z + rb * wbv.z + rc * wc.z, 0.f);
        float v3 = fmaxf(sv.w + ra * wa.w + rb * wbv.w + rc * wc.w, 0.f);
        unsigned int lo = (unsigned int)f2bf(v0) | ((unsigned int)f2bf(v1) << 16);
        unsigned int hi = (unsigned int)f2bf(v2) | ((unsigned int)f2bf(v3) << 16);
        uint2 pk; pk.x = lo; pk.y = hi;
        int byteoff = row * 512 + ((((cg >> 1) ^ (row & 7)) << 4) | ((cg & 1) << 3));
        *(uint2*)(hB + byteoff) = pk;
    }
    __syncthreads();   // B7

    // ---- P7/P8: FC1 h1 = relu(h0 @ W1 + b1); h1 overwrites h0 (reg-buffered)
    {
        const unsigned short* W1t = wbf + 81920;            // [256 n][256 k]
        f32x4 acc[4][4];
        f32x4 z = {0.f, 0.f, 0.f, 0.f};
        #pragma unroll
        for (int m = 0; m < 4; ++m)
            #pragma unroll
            for (int t = 0; t < 4; ++t) acc[m][t] = z;
        for (int ks = 0; ks < 8; ++ks) {
            int k0 = ks * 32 + quad * 8;
            int g  = k0 >> 3;
            bf16x8 a[4], b[4];
            #pragma unroll
            for (int m = 0; m < 4; ++m) {
                int row = m * 16 + l15;
                a[m] = *(const bf16x8*)(hB + row * 512 + ((g ^ (row & 7)) << 4));
            }
            #pragma unroll
            for (int t = 0; t < 4; ++t)
                b[t] = *(const bf16x8*)(W1t + (size_t)(w * 64 + t * 16 + l15) * 256 + k0);
            #pragma unroll
            for (int m = 0; m < 4; ++m)
                #pragma unroll
                for (int t = 0; t < 4; ++t)
                    acc[m][t] = __builtin_amdgcn_mfma_f32_16x16x32_bf16(a[m], b[t], acc[m][t], 0, 0, 0);
        }
        __syncthreads();   // B8: all h0 reads complete before overwrite
        #pragma unroll
        for (int t = 0; t < 4; ++t) {
            int col = w * 64 + t * 16 + l15;
            float bb = b1[col];
            #pragma unroll
            for (int m = 0; m < 4; ++m) {
                #pragma unroll
                for (int r = 0; r < 4; ++r) {
                    int row = m * 16 + quad * 4 + r;
                    int byteoff = row * 512 +
                        ((((col >> 3) ^ (row & 7)) << 4) | ((col & 7) << 1));
                    *(unsigned short*)(hB + byteoff) =
                        f2bf(fmaxf(acc[m][t][r] + bb, 0.f));
                }
            }
        }
    }
    __syncthreads();   // B9

    // ---- P9: FC2 out = relu(h1 @ W2 + b2) -> global fp32
    {
        const unsigned short* W2t = wbf + 147456;
        f32x4 acc[4][4];
        f32x4 z = {0.f, 0.f, 0.f, 0.f};
        #pragma unroll
        for (int m = 0; m < 4; ++m)
            #pragma unroll
            for (int t = 0; t < 4; ++t) acc[m][t] = z;
        for (int ks = 0; ks < 8; ++ks) {
            int k0 = ks * 32 + quad * 8;
            int g  = k0 >> 3;
            bf16x8 a[4], b[4];
            #pragma unroll
            for (int m = 0; m < 4; ++m) {
                int row = m * 16 + l15;
                a[m] = *(const bf16x8*)(hB + row * 512 + ((g ^ (row & 7)) << 4));
            }
            #pragma unroll
            for (int t = 0; t < 4; ++t)
                b[t] = *(const bf16x8*)(W2t + (size_t)(w * 64 + t * 16 + l15) * 256 + k0);
            #pragma unroll
            for (int m = 0; m < 4; ++m)
                #pragma unroll
                for (int t = 0; t < 4; ++t)
                    acc[m][t] = __builtin_amdgcn_mfma_f32_16x16x32_bf16(a[m], b[t], acc[m][t], 0, 0, 0);
        }
        #pragma unroll
        for (int t = 0; t < 4; ++t) {
            int col = w * 64 + t * 16 + l15;
            float bb = b2[col];
            #pragma unroll
            for (int m = 0; m < 4; ++m) {
                #pragma unroll
                for (int r = 0; r < 4; ++r) {
                    int row = m * 16 + quad * 4 + r;
                    out_dec[((size_t)blk * 64 + row) * 256 + col] =
                        fmaxf(acc[m][t][r] + bb, 0.f);
                }
            }
        }
    }
}

// ---------------------------------------------------------------------------
extern "C" void kernel_launch(void* const* d_in, const int* in_sizes, int n_in,
                              void* d_out, int out_size, void* d_ws, size_t ws_size,
                              hipStream_t stream) {
    const float* x    = (const float*)d_in[0];
    const float* Wg0  = (const float*)d_in[1];
    const float* bg0  = (const float*)d_in[2];
    const float* Wg1  = (const float*)d_in[3];
    const float* bg1  = (const float*)d_in[4];
    const float* Wg2  = (const float*)d_in[5];
    const float* bg2  = (const float*)d_in[6];
    const float* Wdec = (const float*)d_in[7];
    const float* bdec = (const float*)d_in[8];
    const float* W0   = (const float*)d_in[9];
    const float* b0   = (const float*)d_in[10];
    const float* W1   = (const float*)d_in[11];
    const float* b1   = (const float*)d_in[12];
    const float* W2   = (const float*)d_in[13];
    const float* b2   = (const float*)d_in[14];

    float* out      = (float*)d_out;
    float* out_rel  = out;                         // [400000, 3]
    float* out_dec  = out + 1200000;               // [400000, 256]
    float* out_clu  = out + 103600000;             // [400000] as float

    unsigned short* wbf = (unsigned short*)d_ws;

    k_prep<<<1248, 256, 0, stream>>>(W0, W1, W2, Wg0, Wg1, Wg2, wbf);
    k_fused<<<NN / NODES, 256, 0, stream>>>(x, bg0, bg1, bg2, Wdec, bdec,
                                            wbf, W0, b0, b1, b2,
                                            out_rel, out_clu, out_dec);
}

// Round 3
// 878.603 us; speedup vs baseline: 1.1766x; 1.1766x over previous
//
#include <hip/hip_runtime.h>
#include <hip/hip_bf16.h>

typedef __attribute__((ext_vector_type(8))) __bf16 bf16x8;
typedef __attribute__((ext_vector_type(4))) float f32x4;
typedef __attribute__((ext_vector_type(4))) unsigned short u16x4;

#define NN 50000
#define TM1 16     // nodes per block, k_global (3125 blocks)
#define PNODES 16  // nodes per block, k_points -> 128 point rows (3125 blocks)

// ws layout (u16 elements):
//   0        : W0t bf16 [256 n][320 k]   (81920)
//   81920    : W1t bf16 [256 n][256 k]   (65536)
//   147456   : W2t bf16 [256 n][256 k]   (65536)
//   212992   : feats bf16 [50000][64]    (3,200,000)
//   3412992  : global split weights (bf16 hi/lo), 106496 elts
#define FEATS_OFF 212992
#define GW_OFF    3412992

__device__ __forceinline__ unsigned short f2bf(float f) {
    unsigned int u = __builtin_bit_cast(unsigned int, f);
    u = (u + 0x7FFFu + ((u >> 16) & 1u)) >> 16;   // RNE; inputs are finite
    return (unsigned short)u;
}
__device__ __forceinline__ float bf2f(unsigned short h) {
    return __builtin_bit_cast(float, (unsigned int)h << 16);
}

// ---------------------------------------------------------------------------
// Prep: point-MLP weights -> bf16 transposed; global-MLP weights -> split
// bf16 hi/lo transposed (fp32-grade MFMA via A_h*W_h + A_l*W_h + A_h*W_l)
// ---------------------------------------------------------------------------
__global__ __launch_bounds__(256) void k_prep(
    const float* __restrict__ W0, const float* __restrict__ W1,
    const float* __restrict__ W2,
    const float* __restrict__ Wg0, const float* __restrict__ Wg1,
    const float* __restrict__ Wg2,
    unsigned short* __restrict__ wbf)
{
    int idx = blockIdx.x * 256 + threadIdx.x;
    if (idx < 81920) {                       // W0t[n][k] = W0[k][n], k<320
        int n = idx / 320, k = idx - n * 320;
        wbf[idx] = f2bf(W0[(size_t)k * 256 + n]);
    } else if (idx < 147456) {               // W1t
        int e = idx - 81920;
        int n = e >> 8, k = e & 255;
        wbf[idx] = f2bf(W1[(size_t)k * 256 + n]);
    } else if (idx < 212992) {               // W2t
        int e = idx - 147456;
        int n = e >> 8, k = e & 255;
        wbf[idx] = f2bf(W2[(size_t)k * 256 + n]);
    } else if (idx < 319488) {               // global weights, split hi/lo
        int e = idx - 212992;                // 0 .. 106495
        float v; int oh, ol;
        if (e < 65536) {                     // Wg0t [256][256]
            int n = e >> 8, k = e & 255;
            v = Wg0[(size_t)k * 256 + n];
            oh = GW_OFF + e; ol = GW_OFF + 65536 + e;
        } else if (e < 98304) {              // Wg1t [128][256]
            int e2 = e - 65536;
            int n = e2 >> 8, k = e2 & 255;
            v = Wg1[(size_t)k * 128 + n];
            oh = GW_OFF + 131072 + e2; ol = GW_OFF + 163840 + e2;
        } else {                             // Wg2t [64][128]
            int e3 = e - 98304;
            int n = e3 >> 7, k = e3 & 127;
            v = Wg2[(size_t)k * 64 + n];
            oh = GW_OFF + 196608 + e3; ol = GW_OFF + 204800 + e3;
        }
        unsigned short h = f2bf(v);
        wbf[oh] = h;
        wbf[ol] = f2bf(v - bf2f(h));
    }
}

// ---------------------------------------------------------------------------
// Kernel 1: global feature MLP on MFMA (bf16x3 split) + decoder + cluster
// 16 nodes/block, 256 threads, LDS 37.9 KB -> 4 blocks/CU (16 waves/CU)
//
// smem (bytes): xh@0 [16][264]u16 (8448) | xl@8448 (8448)
//               q1h@0 [16][136]u16 (4352) | q1l@4352  (alias: xh/xl dead)
//               hh@16896 (8448) | hl@25344 (8448) | g2@33792 f32[16][64] (4096)
// ---------------------------------------------------------------------------
__global__ __launch_bounds__(256, 4) void k_global(
    const float* __restrict__ x,
    const float* __restrict__ bg0, const float* __restrict__ bg1,
    const float* __restrict__ bg2,
    const float* __restrict__ Wdec, const float* __restrict__ bdec,
    const unsigned short* __restrict__ gw,
    unsigned short* __restrict__ feats_bf,
    float* __restrict__ out_rel,
    float* __restrict__ out_cluster)
{
    __shared__ __attribute__((aligned(16))) unsigned char smem[37888];
    unsigned short* xh  = (unsigned short*)(smem);
    unsigned short* xl  = (unsigned short*)(smem + 8448);
    unsigned short* q1h = (unsigned short*)(smem);          // alias (xh dead)
    unsigned short* q1l = (unsigned short*)(smem + 4352);   // alias
    unsigned short* hh  = (unsigned short*)(smem + 16896);
    unsigned short* hl  = (unsigned short*)(smem + 25344);
    float*          g2  = (float*)(smem + 33792);

    const int tid  = threadIdx.x;
    const int lane = tid & 63;
    const int w    = tid >> 6;      // wave id 0..3
    const int quad = lane >> 4;     // 0..3
    const int l15  = lane & 15;
    const int blk  = blockIdx.x;

    // ---- stage 16 node rows, split fp32 -> bf16 hi + lo (float4 loads)
    {
        const float4* xg = (const float4*)(x + (size_t)blk * TM1 * 256);
        #pragma unroll
        for (int it = 0; it < 4; ++it) {
            int e = tid + it * 256;          // 1024 float4 total
            int r = e >> 6, c4 = e & 63;
            float4 v = xg[e];
            u16x4 hv, lv;
            hv[0] = f2bf(v.x); lv[0] = f2bf(v.x - bf2f(hv[0]));
            hv[1] = f2bf(v.y); lv[1] = f2bf(v.y - bf2f(hv[1]));
            hv[2] = f2bf(v.z); lv[2] = f2bf(v.z - bf2f(hv[2]));
            hv[3] = f2bf(v.w); lv[3] = f2bf(v.w - bf2f(hv[3]));
            *(u16x4*)&xh[r * 264 + c4 * 4] = hv;
            *(u16x4*)&xl[r * 264 + c4 * 4] = lv;
        }
    }
    __syncthreads();

    // ---- L0: 256 -> 256  (wave w owns cols [64w, 64w+64))
    {
        const unsigned short* Wh = gw;
        const unsigned short* Wl = gw + 65536;
        f32x4 acc[4];
        f32x4 z = {0.f, 0.f, 0.f, 0.f};
        #pragma unroll
        for (int t = 0; t < 4; ++t) acc[t] = z;
        for (int ks = 0; ks < 8; ++ks) {
            int k0 = ks * 32 + quad * 8;
            bf16x8 ah = *(const bf16x8*)&xh[l15 * 264 + k0];
            bf16x8 al = *(const bf16x8*)&xl[l15 * 264 + k0];
            #pragma unroll
            for (int t = 0; t < 4; ++t) {
                int n = w * 64 + t * 16 + l15;
                bf16x8 bh = *(const bf16x8*)(Wh + (size_t)n * 256 + k0);
                bf16x8 bl = *(const bf16x8*)(Wl + (size_t)n * 256 + k0);
                acc[t] = __builtin_amdgcn_mfma_f32_16x16x32_bf16(ah, bh, acc[t], 0, 0, 0);
                acc[t] = __builtin_amdgcn_mfma_f32_16x16x32_bf16(al, bh, acc[t], 0, 0, 0);
                acc[t] = __builtin_amdgcn_mfma_f32_16x16x32_bf16(ah, bl, acc[t], 0, 0, 0);
            }
        }
        #pragma unroll
        for (int t = 0; t < 4; ++t) {
            int col = w * 64 + t * 16 + l15;
            float bb = bg0[col];
            #pragma unroll
            for (int r = 0; r < 4; ++r) {
                int row = quad * 4 + r;
                float v = fmaxf(acc[t][r] + bb, 0.f);
                unsigned short h = f2bf(v);
                hh[row * 264 + col] = h;
                hl[row * 264 + col] = f2bf(v - bf2f(h));
            }
        }
    }
    __syncthreads();   // xh/xl dead from here; q1 may alias

    // ---- L1: 256 -> 128  (wave w owns cols [32w, 32w+32))
    {
        const unsigned short* Wh = gw + 131072;
        const unsigned short* Wl = gw + 163840;
        f32x4 acc[2];
        f32x4 z = {0.f, 0.f, 0.f, 0.f};
        acc[0] = z; acc[1] = z;
        for (int ks = 0; ks < 8; ++ks) {
            int k0 = ks * 32 + quad * 8;
            bf16x8 ah = *(const bf16x8*)&hh[l15 * 264 + k0];
            bf16x8 al = *(const bf16x8*)&hl[l15 * 264 + k0];
            #pragma unroll
            for (int t = 0; t < 2; ++t) {
                int n = w * 32 + t * 16 + l15;
                bf16x8 bh = *(const bf16x8*)(Wh + (size_t)n * 256 + k0);
                bf16x8 bl = *(const bf16x8*)(Wl + (size_t)n * 256 + k0);
                acc[t] = __builtin_amdgcn_mfma_f32_16x16x32_bf16(ah, bh, acc[t], 0, 0, 0);
                acc[t] = __builtin_amdgcn_mfma_f32_16x16x32_bf16(al, bh, acc[t], 0, 0, 0);
                acc[t] = __builtin_amdgcn_mfma_f32_16x16x32_bf16(ah, bl, acc[t], 0, 0, 0);
            }
        }
        #pragma unroll
        for (int t = 0; t < 2; ++t) {
            int col = w * 32 + t * 16 + l15;
            float bb = bg1[col];
            #pragma unroll
            for (int r = 0; r < 4; ++r) {
                int row = quad * 4 + r;
                float v = fmaxf(acc[t][r] + bb, 0.f);
                unsigned short h = f2bf(v);
                q1h[row * 136 + col] = h;
                q1l[row * 136 + col] = f2bf(v - bf2f(h));
            }
        }
    }
    __syncthreads();

    // ---- L2: 128 -> 64  (wave w owns cols [16w, 16w+16))
    {
        const unsigned short* Wh = gw + 196608;
        const unsigned short* Wl = gw + 204800;
        f32x4 acc = {0.f, 0.f, 0.f, 0.f};
        for (int ks = 0; ks < 4; ++ks) {
            int k0 = ks * 32 + quad * 8;
            bf16x8 ah = *(const bf16x8*)&q1h[l15 * 136 + k0];
            bf16x8 al = *(const bf16x8*)&q1l[l15 * 136 + k0];
            int n = w * 16 + l15;
            bf16x8 bh = *(const bf16x8*)(Wh + (size_t)n * 128 + k0);
            bf16x8 bl = *(const bf16x8*)(Wl + (size_t)n * 128 + k0);
            acc = __builtin_amdgcn_mfma_f32_16x16x32_bf16(ah, bh, acc, 0, 0, 0);
            acc = __builtin_amdgcn_mfma_f32_16x16x32_bf16(al, bh, acc, 0, 0, 0);
            acc = __builtin_amdgcn_mfma_f32_16x16x32_bf16(ah, bl, acc, 0, 0, 0);
        }
        int col = w * 16 + l15;
        float bb = bg2[col];
        #pragma unroll
        for (int r = 0; r < 4; ++r) {
            int row = quad * 4 + r;
            g2[row * 64 + col] = fmaxf(acc[r] + bb, 0.f);
        }
    }
    __syncthreads();

    // ---- feats -> ws as bf16
    {
        const float* src = g2 + tid * 4;
        u16x4 p;
        p[0] = f2bf(src[0]); p[1] = f2bf(src[1]);
        p[2] = f2bf(src[2]); p[3] = f2bf(src[3]);
        *(u16x4*)&feats_bf[(size_t)blk * (TM1 * 64) + tid * 4] = p;
    }

    // ---- decoder head: 16 nodes x 24 outputs, fp32
    for (int tt = tid; tt < TM1 * 24; tt += 256) {
        int m = tt / 24;
        int c = tt - m * 24;
        float acc = bdec[c];
        for (int i = 0; i < 64; ++i) acc += g2[m * 64 + i] * Wdec[i * 24 + c];
        out_rel[(size_t)blk * (TM1 * 24) + tt] = acc;
    }

    // ---- cluster ids (as float): 128 point rows per block
    if (tid < TM1 * 8) {
        out_cluster[(size_t)blk * (TM1 * 8) + tid] = (float)(blk * TM1 + (tid >> 3));
    }
}

// ---------------------------------------------------------------------------
// Kernel 2: per-point MLP via bf16 MFMA, rank-3 fused concat
// 16 nodes = 128 rows / block, 512 threads (8 waves: 2 row-grp x 4 col-grp)
// LDS 68.5 KB -> 2 blocks/CU (16 waves/CU)
//
// smem: h [128 rows][256 cols] bf16 XOR-swizzled @0 (65536 B)
//         xcat [16][336]u16 aliased @0 (10752 B, dead after L0)
//         sP f32[16][256] aliased @49152 (16384 B; all reads into regs
//         before the single barrier, so h writes can't race it)
//       w3 f32[3][256] @65536 (3072) | rl f32[16][24] @68608 (1536)
// ---------------------------------------------------------------------------
__global__ __launch_bounds__(512, 4) void k_points(
    const float* __restrict__ x,
    const unsigned short* __restrict__ feats_bf,
    const float* __restrict__ rel_in,
    const unsigned short* __restrict__ wbf,
    const float* __restrict__ W0f,       // fp32 W0, rows 320..322 (rel cols)
    const float* __restrict__ b0,
    const float* __restrict__ b1,
    const float* __restrict__ b2,
    float* __restrict__ out_dec)
{
    __shared__ __attribute__((aligned(16))) unsigned char smem[70144];
    unsigned char*  hB   = smem;
    unsigned short* xcat = (unsigned short*)smem;             // [16][336]
    float*          sp   = (float*)(smem + 49152);            // [16][256]
    float*          w3   = (float*)(smem + 65536);            // [3][256]
    float*          rl   = (float*)(smem + 68608);            // [16][24]

    const int tid  = threadIdx.x;
    const int lane = tid & 63;
    const int w    = tid >> 6;      // wave id 0..7
    const int wr   = w >> 2;        // row group 0..1 (64 rows)
    const int wc   = w & 3;         // col group 0..3 (64 cols)
    const int quad = lane >> 4;
    const int l15  = lane & 15;
    const int blk  = blockIdx.x;
    const size_t nb = (size_t)blk * PNODES;

    // ---- P0: stage x (bf16), feats (bf16 copy), w3, rl
    {
        const float4* xg = (const float4*)(x + nb * 256);
        #pragma unroll
        for (int it = 0; it < 2; ++it) {
            int e = tid + it * 512;          // 1024 float4 total
            int r = e >> 6, c4 = e & 63;
            float4 v = xg[e];
            u16x4 hv;
            hv[0] = f2bf(v.x); hv[1] = f2bf(v.y);
            hv[2] = f2bf(v.z); hv[3] = f2bf(v.w);
            *(u16x4*)&xcat[r * 336 + c4 * 4] = hv;
        }
        {   // feats: 1024 u16 = 512 u32, one per thread
            int e = tid * 2;
            int r = e >> 6, c = e & 63;
            *(unsigned int*)&xcat[r * 336 + 256 + c] =
                *(const unsigned int*)&feats_bf[nb * 64 + e];
        }
        for (int e = tid; e < 768; e += 512)
            w3[e] = W0f[(size_t)(320 + (e >> 8)) * 256 + (e & 255)];
        if (tid < 384) rl[tid] = rel_in[nb * 24 + tid];
    }
    __syncthreads();   // B1

    // ---- P1: point L0: [16 x 320] @ W0t -> sP (pre-relu, pre-rel, +bias)
    {
        const unsigned short* W0t = wbf;                    // [256 n][320 k]
        f32x4 acc[2];
        f32x4 z = {0.f, 0.f, 0.f, 0.f};
        acc[0] = z; acc[1] = z;
        for (int ks = 0; ks < 10; ++ks) {
            int k0 = ks * 32 + quad * 8;
            bf16x8 a = *(const bf16x8*)&xcat[l15 * 336 + k0];
            #pragma unroll
            for (int t = 0; t < 2; ++t) {
                int n = w * 32 + t * 16 + l15;
                bf16x8 b = *(const bf16x8*)(W0t + (size_t)n * 320 + k0);
                acc[t] = __builtin_amdgcn_mfma_f32_16x16x32_bf16(a, b, acc[t], 0, 0, 0);
            }
        }
        #pragma unroll
        for (int t = 0; t < 2; ++t) {
            int col = w * 32 + t * 16 + l15;
            float bb = b0[col];
            #pragma unroll
            for (int r = 0; r < 4; ++r) {
                int row = quad * 4 + r;
                sp[row * 256 + col] = acc[t][r] + bb;
            }
        }
    }
    __syncthreads();   // B2: sP complete; xcat dead

    // ---- P2: expand sP -> h[128][256] bf16 swizzled, rank-3 rel + relu
    //      wave w owns rows [16w, 16w+16) = nodes 2w, 2w+1
    {
        float4 sv0 = *(const float4*)&sp[(2 * w) * 256 + lane * 4];
        float4 sv1 = *(const float4*)&sp[(2 * w + 1) * 256 + lane * 4];
        float4 wa  = *(const float4*)&w3[lane * 4];
        float4 wb4 = *(const float4*)&w3[256 + lane * 4];
        float4 wc4 = *(const float4*)&w3[512 + lane * 4];
        __syncthreads();   // B3: all sP reads in regs; h writes may begin
        #pragma unroll
        for (int it = 0; it < 16; ++it) {
            int row  = w * 16 + it;
            int node = 2 * w + (it >> 3);
            int p    = it & 7;
            float4 sv = (it < 8) ? sv0 : sv1;
            float ra = rl[node * 24 + p * 3 + 0];
            float rb = rl[node * 24 + p * 3 + 1];
            float rc = rl[node * 24 + p * 3 + 2];
            float v0 = fmaxf(sv.x + ra * wa.x + rb * wb4.x + rc * wc4.x, 0.f);
            float v1 = fmaxf(sv.y + ra * wa.y + rb * wb4.y + rc * wc4.y, 0.f);
            float v2 = fmaxf(sv.z + ra * wa.z + rb * wb4.z + rc * wc4.z, 0.f);
            float v3 = fmaxf(sv.w + ra * wa.w + rb * wb4.w + rc * wc4.w, 0.f);
            unsigned int lo = (unsigned int)f2bf(v0) | ((unsigned int)f2bf(v1) << 16);
            unsigned int hi = (unsigned int)f2bf(v2) | ((unsigned int)f2bf(v3) << 16);
            uint2 pk; pk.x = lo; pk.y = hi;
            int byteoff = row * 512 +
                ((((lane >> 1) ^ (row & 7)) << 4) | ((lane & 1) << 3));
            *(uint2*)(hB + byteoff) = pk;
        }
    }
    __syncthreads();   // B4

    // ---- FC1: h1 = relu(h0 @ W1 + b1); h1 overwrites h0 (reg-buffered)
    {
        const unsigned short* W1t = wbf + 81920;            // [256 n][256 k]
        f32x4 acc[4][4];
        f32x4 z = {0.f, 0.f, 0.f, 0.f};
        #pragma unroll
        for (int m = 0; m < 4; ++m)
            #pragma unroll
            for (int t = 0; t < 4; ++t) acc[m][t] = z;
        for (int ks = 0; ks < 8; ++ks) {
            int k0 = ks * 32 + quad * 8;
            int g  = k0 >> 3;
            bf16x8 a[4], b[4];
            #pragma unroll
            for (int m = 0; m < 4; ++m) {
                int row = wr * 64 + m * 16 + l15;
                a[m] = *(const bf16x8*)(hB + row * 512 + ((g ^ (row & 7)) << 4));
            }
            #pragma unroll
            for (int t = 0; t < 4; ++t)
                b[t] = *(const bf16x8*)(W1t + (size_t)(wc * 64 + t * 16 + l15) * 256 + k0);
            #pragma unroll
            for (int m = 0; m < 4; ++m)
                #pragma unroll
                for (int t = 0; t < 4; ++t)
                    acc[m][t] = __builtin_amdgcn_mfma_f32_16x16x32_bf16(a[m], b[t], acc[m][t], 0, 0, 0);
        }
        __syncthreads();   // B5: all h0 reads complete before overwrite
        #pragma unroll
        for (int t = 0; t < 4; ++t) {
            int col = wc * 64 + t * 16 + l15;
            float bb = b1[col];
            #pragma unroll
            for (int m = 0; m < 4; ++m) {
                #pragma unroll
                for (int r = 0; r < 4; ++r) {
                    int row = wr * 64 + m * 16 + quad * 4 + r;
                    int byteoff = row * 512 +
                        ((((col >> 3) ^ (row & 7)) << 4) | ((col & 7) << 1));
                    *(unsigned short*)(hB + byteoff) =
                        f2bf(fmaxf(acc[m][t][r] + bb, 0.f));
                }
            }
        }
    }
    __syncthreads();   // B6

    // ---- FC2: out = relu(h1 @ W2 + b2) -> global fp32
    {
        const unsigned short* W2t = wbf + 147456;
        f32x4 acc[4][4];
        f32x4 z = {0.f, 0.f, 0.f, 0.f};
        #pragma unroll
        for (int m = 0; m < 4; ++m)
            #pragma unroll
            for (int t = 0; t < 4; ++t) acc[m][t] = z;
        for (int ks = 0; ks < 8; ++ks) {
            int k0 = ks * 32 + quad * 8;
            int g  = k0 >> 3;
            bf16x8 a[4], b[4];
            #pragma unroll
            for (int m = 0; m < 4; ++m) {
                int row = wr * 64 + m * 16 + l15;
                a[m] = *(const bf16x8*)(hB + row * 512 + ((g ^ (row & 7)) << 4));
            }
            #pragma unroll
            for (int t = 0; t < 4; ++t)
                b[t] = *(const bf16x8*)(W2t + (size_t)(wc * 64 + t * 16 + l15) * 256 + k0);
            #pragma unroll
            for (int m = 0; m < 4; ++m)
                #pragma unroll
                for (int t = 0; t < 4; ++t)
                    acc[m][t] = __builtin_amdgcn_mfma_f32_16x16x32_bf16(a[m], b[t], acc[m][t], 0, 0, 0);
        }
        #pragma unroll
        for (int t = 0; t < 4; ++t) {
            int col = wc * 64 + t * 16 + l15;
            float bb = b2[col];
            #pragma unroll
            for (int m = 0; m < 4; ++m) {
                #pragma unroll
                for (int r = 0; r < 4; ++r) {
                    int row = wr * 64 + m * 16 + quad * 4 + r;
                    out_dec[((size_t)blk * 128 + row) * 256 + col] =
                        fmaxf(acc[m][t][r] + bb, 0.f);
                }
            }
        }
    }
}

// ---------------------------------------------------------------------------
extern "C" void kernel_launch(void* const* d_in, const int* in_sizes, int n_in,
                              void* d_out, int out_size, void* d_ws, size_t ws_size,
                              hipStream_t stream) {
    const float* x    = (const float*)d_in[0];
    const float* Wg0  = (const float*)d_in[1];
    const float* bg0  = (const float*)d_in[2];
    const float* Wg1  = (const float*)d_in[3];
    const float* bg1  = (const float*)d_in[4];
    const float* Wg2  = (const float*)d_in[5];
    const float* bg2  = (const float*)d_in[6];
    const float* Wdec = (const float*)d_in[7];
    const float* bdec = (const float*)d_in[8];
    const float* W0   = (const float*)d_in[9];
    const float* b0   = (const float*)d_in[10];
    const float* W1   = (const float*)d_in[11];
    const float* b1   = (const float*)d_in[12];
    const float* W2   = (const float*)d_in[13];
    const float* b2   = (const float*)d_in[14];

    float* out      = (float*)d_out;
    float* out_rel  = out;                         // [400000, 3]
    float* out_dec  = out + 1200000;               // [400000, 256]
    float* out_clu  = out + 103600000;             // [400000] as float

    unsigned short* wbf      = (unsigned short*)d_ws;
    unsigned short* feats_bf = wbf + FEATS_OFF;    // [50000, 64] bf16
    unsigned short* gw       = wbf + GW_OFF;       // split global weights

    k_prep<<<1248, 256, 0, stream>>>(W0, W1, W2, Wg0, Wg1, Wg2, wbf);
    k_global<<<NN / TM1, 256, 0, stream>>>(x, bg0, bg1, bg2, Wdec, bdec, gw,
                                           feats_bf, out_rel, out_clu);
    k_points<<<NN / PNODES, 512, 0, stream>>>(x, feats_bf, out_rel,
                                              wbf, W0, b0, b1, b2, out_dec);
}